// Round 1
// baseline (1261.666 us; speedup 1.0000x reference)
//
#include <hip/hip_runtime.h>

#define B_    1024
#define L_    200
#define M_    (B_ * L_)     // 204800
#define E_    128
#define C_    384
#define K_    384
#define OUT_  10000

typedef __attribute__((ext_vector_type(8))) short bf16x8;
typedef __attribute__((ext_vector_type(4))) float f32x4;
typedef unsigned short u16;

__device__ __forceinline__ u16 f2bf(float f) {
    union { float f; unsigned u; } v; v.f = f;
    unsigned u = v.u;
    unsigned r = (u + 0x7fffu + ((u >> 16) & 1u)) >> 16;  // RNE; inputs never NaN
    return (u16)r;
}
__device__ __forceinline__ float bf2f(u16 s) {
    union { unsigned u; float f; } v; v.u = ((unsigned)s) << 16; return v.f;
}

// ---------------- convert f32 -> bf16 (vectorized) ----------------
__global__ void cvt_bf16_kernel(const float4* __restrict__ src,
                                ushort4* __restrict__ dst, int n4) {
    int i = blockIdx.x * 256 + threadIdx.x;
    if (i < n4) {
        float4 v = src[i];
        ushort4 o;
        o.x = f2bf(v.x); o.y = f2bf(v.y); o.z = f2bf(v.z); o.w = f2bf(v.w);
        dst[i] = o;
    }
}

// ---------------- fused gather + FC GEMM + tanh + score ----------------
// Block: 256 thr (4 waves). Tile: 64 rows (m) x 384 cols (c), K=384.
// A = gathered ctx (bf16 in LDS), B-frags direct from global W_fc (bf16, L2-hot).
__global__ __launch_bounds__(256, 2)
void fc_kernel(const int* __restrict__ starts, const int* __restrict__ paths,
               const int* __restrict__ ends,
               const float* __restrict__ node_emb, const float* __restrict__ path_emb,
               const u16* __restrict__ wfc, const float* __restrict__ a_vec,
               u16* __restrict__ h_out, float* __restrict__ scores) {
    __shared__ u16 Alds[64 * 392];   // row stride 392 (=384+8) keeps 16B align, kills bank conflicts
    __shared__ int idx_s[192];       // [seg][row]
    const int tid = threadIdx.x;
    const int m0 = blockIdx.x * 64;

    if (tid < 192) {
        int r = tid & 63, s = tid >> 6;
        int m = m0 + r;
        idx_s[tid] = (s == 0) ? starts[m] : (s == 1) ? paths[m] : ends[m];
    }
    __syncthreads();

    // stage 64 rows x 384 f32 -> bf16 LDS. 96 float4 per row; 24 iters x 256 thr.
    #pragma unroll
    for (int it = 0; it < 24; ++it) {
        int gid = it * 256 + tid;
        int row = gid / 96;
        int q   = gid - row * 96;
        int seg = q >> 5;
        int c4  = q & 31;
        const float* table = (seg == 1) ? path_emb : node_emb;
        long idx = idx_s[(seg << 6) + row];
        float4 v = *(const float4*)(table + idx * 128 + c4 * 4);
        ushort4 o;
        o.x = f2bf(v.x); o.y = f2bf(v.y); o.z = f2bf(v.z); o.w = f2bf(v.w);
        *(ushort4*)(&Alds[row * 392 + (seg << 7) + (c4 << 2)]) = o;
    }
    __syncthreads();

    const int lane = tid & 63;
    const int wave = tid >> 6;
    const int lrow = lane & 15;   // m within 16 (A) / n within 16 (B)
    const int quad = lane >> 4;   // k-quad

    f32x4 acc[24];
    #pragma unroll
    for (int i = 0; i < 24; ++i) acc[i] = (f32x4){0.f, 0.f, 0.f, 0.f};

    const u16* aBase = &Alds[(wave * 16 + lrow) * 392 + quad * 8];
    const u16* bBase = wfc + lrow * 384 + quad * 8;

    for (int kk = 0; kk < 12; ++kk) {
        bf16x8 af = *(const bf16x8*)(aBase + kk * 32);
        #pragma unroll
        for (int n0 = 0; n0 < 24; ++n0) {
            bf16x8 bfr = *(const bf16x8*)(bBase + n0 * (16 * 384) + kk * 32);
            acc[n0] = __builtin_amdgcn_mfma_f32_16x16x32_bf16(af, bfr, acc[n0], 0, 0, 0);
        }
    }

    // epilogue: tanh, store h (bf16), attention score = h . a
    float avals[24];
    #pragma unroll
    for (int n0 = 0; n0 < 24; ++n0) avals[n0] = a_vec[n0 * 16 + lrow];

    float sc0 = 0.f, sc1 = 0.f, sc2 = 0.f, sc3 = 0.f;
    const int mrow = m0 + wave * 16 + quad * 4;  // D row = quad*4 + r, col = lrow
    #pragma unroll
    for (int n0 = 0; n0 < 24; ++n0) {
        int col = n0 * 16 + lrow;
        #pragma unroll
        for (int r = 0; r < 4; ++r) {
            float pre = acc[n0][r];
            float e = __expf(2.0f * pre);
            float h = 1.0f - 2.0f / (e + 1.0f);   // tanh
            h_out[(long)(mrow + r) * 384 + col] = f2bf(h);
            float hs = h * avals[n0];
            if      (r == 0) sc0 += hs;
            else if (r == 1) sc1 += hs;
            else if (r == 2) sc2 += hs;
            else             sc3 += hs;
        }
    }
    #pragma unroll
    for (int off = 1; off < 16; off <<= 1) {
        sc0 += __shfl_xor(sc0, off);
        sc1 += __shfl_xor(sc1, off);
        sc2 += __shfl_xor(sc2, off);
        sc3 += __shfl_xor(sc3, off);
    }
    if (lrow == 0) {
        scores[mrow + 0] = sc0;
        scores[mrow + 1] = sc1;
        scores[mrow + 2] = sc2;
        scores[mrow + 3] = sc3;
    }
}

// ---------------- softmax over L=200 per batch row (1 wave/block) ----------------
__global__ void softmax_kernel(const float* __restrict__ scores, float* __restrict__ attn) {
    int b = blockIdx.x;
    int t = threadIdx.x;  // 0..63
    const float* s = scores + b * L_;
    float v0 = s[t];
    float v1 = s[t + 64];
    float v2 = s[t + 128];                           // t+128 <= 191 < 200
    float v3 = (t < 8) ? s[t + 192] : -INFINITY;     // 192..199
    float mx = fmaxf(fmaxf(v0, v1), fmaxf(v2, v3));
    #pragma unroll
    for (int off = 1; off < 64; off <<= 1) mx = fmaxf(mx, __shfl_xor(mx, off));
    float e0 = __expf(v0 - mx), e1 = __expf(v1 - mx), e2 = __expf(v2 - mx);
    float e3 = (t < 8) ? __expf(v3 - mx) : 0.f;
    float sum = e0 + e1 + e2 + e3;
    #pragma unroll
    for (int off = 1; off < 64; off <<= 1) sum += __shfl_xor(sum, off);
    float inv = 1.f / sum;
    float* o = attn + b * L_;
    o[t] = e0 * inv; o[t + 64] = e1 * inv; o[t + 128] = e2 * inv;
    if (t < 8) o[t + 192] = e3 * inv;
}

// ---------------- code_vectors = sum_l attn * h ----------------
__global__ void codevec_kernel(const u16* __restrict__ h, const float* __restrict__ attn,
                               u16* __restrict__ cv) {
    int b = blockIdx.x;
    int c = threadIdx.x;  // 384 threads
    const u16* hp = h + (long)b * (L_ * 384) + c;
    const float* ap = attn + b * L_;
    float s = 0.f;
    #pragma unroll 4
    for (int l = 0; l < L_; ++l) s += bf2f(hp[(long)l * 384]) * ap[l];
    cv[b * 384 + c] = f2bf(s);
}

// ---------------- out = cv @ W_out^T + b_out ----------------
// Block: 256 thr (4 waves). Tile 64 (m) x 256 (n), K=384. No LDS: A and B frags
// straight from global (cv is 768 KB, L2-hot; W_out bf16 7.7 MB).
__global__ __launch_bounds__(256, 2)
void out_gemm_kernel(const u16* __restrict__ cv, const u16* __restrict__ wout,
                     const float* __restrict__ b_out, float* __restrict__ out) {
    const int tid = threadIdx.x;
    const int lane = tid & 63, wave = tid >> 6;
    const int lrow = lane & 15, quad = lane >> 4;
    const int m0  = blockIdx.x * 64;
    const int n0b = blockIdx.y * 256;

    f32x4 acc[16];
    #pragma unroll
    for (int i = 0; i < 16; ++i) acc[i] = (f32x4){0.f, 0.f, 0.f, 0.f};

    const u16* aB = cv + (m0 + wave * 16 + lrow) * 384 + quad * 8;
    for (int kk = 0; kk < 12; ++kk) {
        bf16x8 af = *(const bf16x8*)(aB + kk * 32);
        #pragma unroll
        for (int t = 0; t < 16; ++t) {
            int n = n0b + t * 16 + lrow;
            n = (n < OUT_) ? n : (OUT_ - 1);   // clamp OOB loads; stores masked below
            bf16x8 bfr = *(const bf16x8*)(wout + (long)n * 384 + kk * 32 + quad * 8);
            acc[t] = __builtin_amdgcn_mfma_f32_16x16x32_bf16(af, bfr, acc[t], 0, 0, 0);
        }
    }
    const int mrow = m0 + wave * 16 + quad * 4;
    #pragma unroll
    for (int t = 0; t < 16; ++t) {
        int n = n0b + t * 16 + lrow;
        if (n < OUT_) {
            float bias = b_out[n];
            #pragma unroll
            for (int r = 0; r < 4; ++r)
                out[(long)(mrow + r) * OUT_ + n] = acc[t][r] + bias;
        }
    }
}

extern "C" void kernel_launch(void* const* d_in, const int* in_sizes, int n_in,
                              void* d_out, int out_size, void* d_ws, size_t ws_size,
                              hipStream_t stream) {
    const int*   starts   = (const int*)d_in[0];
    const int*   paths    = (const int*)d_in[1];
    const int*   ends     = (const int*)d_in[2];
    const float* node_emb = (const float*)d_in[3];
    const float* path_emb = (const float*)d_in[4];
    const float* W_fc     = (const float*)d_in[5];
    const float* a_vec    = (const float*)d_in[6];
    const float* W_out    = (const float*)d_in[7];
    const float* b_out    = (const float*)d_in[8];
    float* out = (float*)d_out;

    char* ws = (char*)d_ws;
    u16*   h_bf16 = (u16*)ws;   ws += (size_t)M_ * 384 * 2;     // 157,286,400
    float* scores = (float*)ws; ws += (size_t)M_ * 4;           //     819,200
    float* attn   = (float*)ws; ws += (size_t)M_ * 4;           //     819,200
    u16*   wfc_b  = (u16*)ws;   ws += (size_t)C_ * K_ * 2;      //     294,912
    u16*   wout_b = (u16*)ws;   ws += (size_t)OUT_ * K_ * 2;    //   7,680,000
    u16*   cv_b   = (u16*)ws;   ws += (size_t)B_ * C_ * 2;      //     786,432

    cvt_bf16_kernel<<<(C_ * K_ / 4 + 255) / 256, 256, 0, stream>>>(
        (const float4*)W_fc, (ushort4*)wfc_b, C_ * K_ / 4);
    cvt_bf16_kernel<<<(OUT_ * K_ / 4 + 255) / 256, 256, 0, stream>>>(
        (const float4*)W_out, (ushort4*)wout_b, OUT_ * K_ / 4);
    fc_kernel<<<M_ / 64, 256, 0, stream>>>(
        starts, paths, ends, node_emb, path_emb, wfc_b, a_vec, h_bf16, scores);
    softmax_kernel<<<B_, 64, 0, stream>>>(scores, attn);
    codevec_kernel<<<B_, 384, 0, stream>>>(h_bf16, attn, cv_b);
    out_gemm_kernel<<<dim3(16, 40), 256, 0, stream>>>(cv_b, wout_b, b_out, out);
}

// Round 3
// 977.384 us; speedup vs baseline: 1.2909x; 1.2909x over previous
//
#include <hip/hip_runtime.h>

#define B_    1024
#define L_    200
#define M_    (B_ * L_)     // 204800
#define E_    128
#define C_    384
#define K_    384
#define OUT_  10000

typedef __attribute__((ext_vector_type(8))) short bf16x8;
typedef __attribute__((ext_vector_type(4))) float f32x4;
typedef unsigned short u16;

__device__ __forceinline__ u16 f2bf(float f) {
    union { float f; unsigned u; } v; v.f = f;
    unsigned u = v.u;
    unsigned r = (u + 0x7fffu + ((u >> 16) & 1u)) >> 16;  // RNE
    return (u16)r;
}
__device__ __forceinline__ float bf2f(u16 s) {
    union { unsigned u; float f; } v; v.u = ((unsigned)s) << 16; return v.f;
}

// async global->LDS: per-lane global src, wave-uniform LDS base + lane*size dest
#define GLD16(g, l) __builtin_amdgcn_global_load_lds((const __attribute__((address_space(1))) void*)(g), \
                        (__attribute__((address_space(3))) void*)(l), 16, 0, 0)
#define GLD4(g, l)  __builtin_amdgcn_global_load_lds((const __attribute__((address_space(1))) void*)(g), \
                        (__attribute__((address_space(3))) void*)(l), 4, 0, 0)

// ---------------- convert f32 -> bf16 (vectorized) ----------------
__global__ void cvt_bf16_kernel(const float4* __restrict__ src,
                                ushort4* __restrict__ dst, int n4) {
    int i = blockIdx.x * 256 + threadIdx.x;
    if (i < n4) {
        float4 v = src[i];
        ushort4 o;
        o.x = f2bf(v.x); o.y = f2bf(v.y); o.z = f2bf(v.z); o.w = f2bf(v.w);
        dst[i] = o;
    }
}

// ---------------- fused gather + FC GEMM + tanh + score ----------------
// Tile: 32 rows x 384 cols. Stage ctx f32 via global_load_lds (zero VGPR,
// 24 outstanding issues/wave), convert once to bf16 in place, MFMA K-loop.
// LDS 49,664+512 B -> 3 blocks/CU with launch_bounds(256,3).
__global__ __launch_bounds__(256, 3)
void fc_kernel(const int* __restrict__ starts, const int* __restrict__ paths,
               const int* __restrict__ ends,
               const float* __restrict__ node_emb, const float* __restrict__ path_emb,
               const u16* __restrict__ wfc, const float* __restrict__ a_vec,
               u16* __restrict__ h_out, float* __restrict__ scores) {
    __shared__ float Af32[32 * 388];   // f32 staging; row stride 388 floats (1552 B)
    __shared__ float scpart[4][32];
    u16* Ab = (u16*)Af32;              // bf16 view, row stride 392 u16 (overlays first 25 KB)

    const int tid  = threadIdx.x;
    const int lane = tid & 63;
    const int wave = tid >> 6;
    const int m0   = blockIdx.x * 32;

    // ---- stage: 3 async issues per row, 8 rows per wave ----
    {
        const int half = lane >> 5;    // 0: start-seg (node), 1: path-seg
        const int l32  = lane & 31;
        #pragma unroll
        for (int rr = 0; rr < 8; ++rr) {
            const int r = wave * 8 + rr;
            const int m = m0 + r;
            long si = starts[m];
            long pi = paths[m];
            long ei = ends[m];
            // segs 0+1: 1024 B, lanes 0-31 from node row, 32-63 from path row
            const float* s01 = half ? (path_emb + pi * 128 + l32 * 4)
                                    : (node_emb + si * 128 + l32 * 4);
            GLD16(s01, &Af32[r * 388]);
            // seg 2: 512 B from node row (ends), two 256-B issues
            GLD4(node_emb + ei * 128 + lane,      &Af32[r * 388 + 256]);
            GLD4(node_emb + ei * 128 + 64 + lane, &Af32[r * 388 + 320]);
        }
    }
    __syncthreads();   // drains vmcnt -> all ctx f32 in LDS

    // ---- cooperative in-place f32 -> bf16 convert (each element once) ----
    // 32 rows x 96 data-float4 = 3072 slots = 12 iters x 256 threads.
    // Read ALL before writing ANY (barrier) -> in-place overlay is race-free.
    float4 tv[12];
    #pragma unroll
    for (int i = 0; i < 12; ++i) {
        int f = i * 256 + tid;          // 0..3071
        int r = f / 96;
        int c4 = f - r * 96;
        tv[i] = *(const float4*)&Af32[r * 388 + c4 * 4];
    }
    __syncthreads();
    #pragma unroll
    for (int i = 0; i < 12; ++i) {
        int f = i * 256 + tid;
        int r = f / 96;
        int c4 = f - r * 96;
        ushort4 o;
        o.x = f2bf(tv[i].x); o.y = f2bf(tv[i].y);
        o.z = f2bf(tv[i].z); o.w = f2bf(tv[i].w);
        *(ushort4*)&Ab[r * 392 + c4 * 4] = o;
    }
    __syncthreads();

    // ---- K-loop: wave covers all 32 rows (2 m-tiles) x 6 n0-tiles (96 cols) ----
    const int lrow = lane & 15;
    const int quad = lane >> 4;

    f32x4 acc[2][6];
    #pragma unroll
    for (int mt = 0; mt < 2; ++mt)
        #pragma unroll
        for (int j = 0; j < 6; ++j) acc[mt][j] = (f32x4){0.f, 0.f, 0.f, 0.f};

    const u16* aB0 = &Ab[lrow * 392 + quad * 8];
    const u16* aB1 = &Ab[(16 + lrow) * 392 + quad * 8];
    const u16* bB  = wfc + (wave * 96 + lrow) * 384 + quad * 8;

    for (int kk = 0; kk < 12; ++kk) {
        bf16x8 a0 = *(const bf16x8*)(aB0 + kk * 32);
        bf16x8 a1 = *(const bf16x8*)(aB1 + kk * 32);
        #pragma unroll
        for (int j = 0; j < 6; ++j) {
            bf16x8 bfr = *(const bf16x8*)(bB + j * (16 * 384) + kk * 32);
            acc[0][j] = __builtin_amdgcn_mfma_f32_16x16x32_bf16(a0, bfr, acc[0][j], 0, 0, 0);
            acc[1][j] = __builtin_amdgcn_mfma_f32_16x16x32_bf16(a1, bfr, acc[1][j], 0, 0, 0);
        }
    }

    // ---- epilogue: tanh, h store, score partials ----
    float sc00 = 0.f, sc01 = 0.f, sc02 = 0.f, sc03 = 0.f;
    float sc10 = 0.f, sc11 = 0.f, sc12 = 0.f, sc13 = 0.f;
    #pragma unroll
    for (int j = 0; j < 6; ++j) {
        const int col = (wave * 6 + j) * 16 + lrow;
        const float av = a_vec[col];
        #pragma unroll
        for (int mt = 0; mt < 2; ++mt) {
            const int mrow = m0 + mt * 16 + quad * 4;
            #pragma unroll
            for (int r = 0; r < 4; ++r) {
                float pre = acc[mt][j][r];
                float e = __expf(2.0f * pre);
                float hv = 1.0f - 2.0f / (e + 1.0f);
                h_out[(long)(mrow + r) * 384 + col] = f2bf(hv);
                float hs = hv * av;
                if (mt == 0) {
                    if      (r == 0) sc00 += hs; else if (r == 1) sc01 += hs;
                    else if (r == 2) sc02 += hs; else             sc03 += hs;
                } else {
                    if      (r == 0) sc10 += hs; else if (r == 1) sc11 += hs;
                    else if (r == 2) sc12 += hs; else             sc13 += hs;
                }
            }
        }
    }
    #pragma unroll
    for (int off = 1; off < 16; off <<= 1) {
        sc00 += __shfl_xor(sc00, off); sc01 += __shfl_xor(sc01, off);
        sc02 += __shfl_xor(sc02, off); sc03 += __shfl_xor(sc03, off);
        sc10 += __shfl_xor(sc10, off); sc11 += __shfl_xor(sc11, off);
        sc12 += __shfl_xor(sc12, off); sc13 += __shfl_xor(sc13, off);
    }
    if (lrow == 0) {
        scpart[wave][quad * 4 + 0] = sc00;
        scpart[wave][quad * 4 + 1] = sc01;
        scpart[wave][quad * 4 + 2] = sc02;
        scpart[wave][quad * 4 + 3] = sc03;
        scpart[wave][16 + quad * 4 + 0] = sc10;
        scpart[wave][16 + quad * 4 + 1] = sc11;
        scpart[wave][16 + quad * 4 + 2] = sc12;
        scpart[wave][16 + quad * 4 + 3] = sc13;
    }
    __syncthreads();
    if (tid < 32)
        scores[m0 + tid] = scpart[0][tid] + scpart[1][tid] + scpart[2][tid] + scpart[3][tid];
}

// ---------------- softmax over L=200 per batch row (1 wave/block) ----------------
__global__ void softmax_kernel(const float* __restrict__ scores, float* __restrict__ attn) {
    int b = blockIdx.x;
    int t = threadIdx.x;
    const float* s = scores + b * L_;
    float v0 = s[t];
    float v1 = s[t + 64];
    float v2 = s[t + 128];
    float v3 = (t < 8) ? s[t + 192] : -INFINITY;
    float mx = fmaxf(fmaxf(v0, v1), fmaxf(v2, v3));
    #pragma unroll
    for (int off = 1; off < 64; off <<= 1) mx = fmaxf(mx, __shfl_xor(mx, off));
    float e0 = __expf(v0 - mx), e1 = __expf(v1 - mx), e2 = __expf(v2 - mx);
    float e3 = (t < 8) ? __expf(v3 - mx) : 0.f;
    float sum = e0 + e1 + e2 + e3;
    #pragma unroll
    for (int off = 1; off < 64; off <<= 1) sum += __shfl_xor(sum, off);
    float inv = 1.f / sum;
    float* o = attn + b * L_;
    o[t] = e0 * inv; o[t + 64] = e1 * inv; o[t + 128] = e2 * inv;
    if (t < 8) o[t + 192] = e3 * inv;
}

// ---------------- code_vectors = sum_l attn * h (bf16x8 loads, 4-wave L split) ----
__global__ __launch_bounds__(256)
void codevec_kernel(const u16* __restrict__ h, const float* __restrict__ attn,
                    u16* __restrict__ cv) {
    __shared__ float part[4][384];
    const int b = blockIdx.x;
    const int tid = threadIdx.x, lane = tid & 63, wave = tid >> 6;
    float acc[8];
    #pragma unroll
    for (int e = 0; e < 8; ++e) acc[e] = 0.f;
    if (lane < 48) {
        const u16* hp = h + (long)b * (L_ * 384) + lane * 8;
        const float* ap = attn + b * L_;
        #pragma unroll 10
        for (int l = wave; l < L_; l += 4) {
            float w = ap[l];
            bf16x8 v = *(const bf16x8*)(hp + (long)l * 384);
            #pragma unroll
            for (int e = 0; e < 8; ++e) acc[e] += bf2f((u16)v[e]) * w;
        }
        #pragma unroll
        for (int e = 0; e < 8; ++e) part[wave][lane * 8 + e] = acc[e];
    }
    __syncthreads();
    for (int c = tid; c < 384; c += 256) {
        cv[b * 384 + c] = f2bf(part[0][c] + part[1][c] + part[2][c] + part[3][c]);
    }
}

// ---------------- out = cv @ W_out^T + b_out ----------------
// Tile 64(m) x 128(n), grid 16 x 79 = 1264 blocks (~5/CU). All 4 waves share
// the same B-frags (L1-hot); A from L2-hot cv.
__global__ __launch_bounds__(256, 4)
void out_gemm_kernel(const u16* __restrict__ cv, const u16* __restrict__ wout,
                     const float* __restrict__ b_out, float* __restrict__ out) {
    const int tid = threadIdx.x;
    const int lane = tid & 63, wave = tid >> 6;
    const int lrow = lane & 15, quad = lane >> 4;
    const int m0  = blockIdx.x * 64 + wave * 16;
    const int n0b = blockIdx.y * 128;

    f32x4 acc[8];
    #pragma unroll
    for (int i = 0; i < 8; ++i) acc[i] = (f32x4){0.f, 0.f, 0.f, 0.f};

    const u16* aB = cv + (m0 + lrow) * 384 + quad * 8;
    for (int kk = 0; kk < 12; ++kk) {
        bf16x8 af = *(const bf16x8*)(aB + kk * 32);
        #pragma unroll
        for (int t = 0; t < 8; ++t) {
            int n = n0b + t * 16 + lrow;
            n = (n < OUT_) ? n : (OUT_ - 1);
            bf16x8 bfr = *(const bf16x8*)(wout + (long)n * 384 + kk * 32 + quad * 8);
            acc[t] = __builtin_amdgcn_mfma_f32_16x16x32_bf16(af, bfr, acc[t], 0, 0, 0);
        }
    }
    const int mrow = m0 + quad * 4;
    #pragma unroll
    for (int t = 0; t < 8; ++t) {
        int n = n0b + t * 16 + lrow;
        if (n < OUT_) {
            float bias = b_out[n];
            #pragma unroll
            for (int r = 0; r < 4; ++r)
                out[(long)(mrow + r) * OUT_ + n] = acc[t][r] + bias;
        }
    }
}

extern "C" void kernel_launch(void* const* d_in, const int* in_sizes, int n_in,
                              void* d_out, int out_size, void* d_ws, size_t ws_size,
                              hipStream_t stream) {
    const int*   starts   = (const int*)d_in[0];
    const int*   paths    = (const int*)d_in[1];
    const int*   ends     = (const int*)d_in[2];
    const float* node_emb = (const float*)d_in[3];
    const float* path_emb = (const float*)d_in[4];
    const float* W_fc     = (const float*)d_in[5];
    const float* a_vec    = (const float*)d_in[6];
    const float* W_out    = (const float*)d_in[7];
    const float* b_out    = (const float*)d_in[8];
    float* out = (float*)d_out;

    char* ws = (char*)d_ws;
    u16*   h_bf16 = (u16*)ws;   ws += (size_t)M_ * 384 * 2;
    float* scores = (float*)ws; ws += (size_t)M_ * 4;
    float* attn   = (float*)ws; ws += (size_t)M_ * 4;
    u16*   wfc_b  = (u16*)ws;   ws += (size_t)C_ * K_ * 2;
    u16*   wout_b = (u16*)ws;   ws += (size_t)OUT_ * K_ * 2;
    u16*   cv_b   = (u16*)ws;   ws += (size_t)B_ * C_ * 2;

    cvt_bf16_kernel<<<(C_ * K_ / 4 + 255) / 256, 256, 0, stream>>>(
        (const float4*)W_fc, (ushort4*)wfc_b, C_ * K_ / 4);
    cvt_bf16_kernel<<<(OUT_ * K_ / 4 + 255) / 256, 256, 0, stream>>>(
        (const float4*)W_out, (ushort4*)wout_b, OUT_ * K_ / 4);
    fc_kernel<<<M_ / 32, 256, 0, stream>>>(
        starts, paths, ends, node_emb, path_emb, wfc_b, a_vec, h_bf16, scores);
    softmax_kernel<<<B_, 64, 0, stream>>>(scores, attn);
    codevec_kernel<<<B_, 256, 0, stream>>>(h_bf16, attn, cv_b);
    out_gemm_kernel<<<dim3(16, 79), 256, 0, stream>>>(cv_b, wout_b, b_out, out);
}